// Round 1
// baseline (683.147 us; speedup 1.0000x reference)
//
#include <hip/hip_runtime.h>
#include <cmath>
#include <cstdint>

// ---------------- static configuration ----------------
// B=32, T=4096, C=3, 128 scales, out 224x224, N_PSI=4096, pad=2047.
// sig = c*32 + b  (96 signals), padded signal length 8190 (store 8192).
// Composite kernel per (scale, class): class 0..6 = interior phase (w mod 7),
// class 7 = w==0 (left-clipped), class 8 = w==223 (right-clipped).
// H rows: [160 zero guard][<=3308 data, 4-aligned][>=160 zero guard], stride 3776 floats.

constexpr int C_TP     = 8190;
constexpr int C_XROWS  = 8192;   // time rows in xpT
constexpr int C_SIGP   = 128;    // padded signals (96 real)
constexpr long long C_HSTRIDE = 3776;
constexpr int C_HGUARD = 160;
constexpr int C_NCLS   = 9;
constexpr int C_RW     = 8;      // w's per chunk
constexpr int C_NW     = 224;

// Replicate numpy: scales = logspace(log10(2), log10(204), 128).astype(f32);
// K = ceil(16*s + 1); d = (4094-K)//2; a = s * (16/4095) in double.
__device__ __forceinline__ void scale_params(int i, float& s32, int& K, int& d, double& a) {
  const double l2   = log10(2.0);
  const double l204 = log10(204.0);
  double step = (l204 - l2) / 127.0;
  double e = (i == 127) ? l204 : ((double)i * step + l2);
  double sv = pow(10.0, e);
  s32 = (float)sv;
  double sp = (double)s32;
  K = (int)ceil(sp * 16.0 + 1.0);
  d = (4094 - K) >> 1;
  a = sp * (16.0 / 4095.0);
}

// ---------------- build reflect-padded, transposed signals ----------------
// xpT[p][sig], p in [0,8192), sig in [0,128). zeros outside real data.
__global__ void k_build_xp(const float* __restrict__ x, float* __restrict__ xpT) {
  int idx = blockIdx.x * blockDim.x + threadIdx.x;   // 8192*128 threads
  int p   = idx >> 7;
  int sig = idx & 127;
  float val = 0.f;
  if (sig < 96 && p < C_TP) {
    int c = sig >> 5;
    int b = sig & 31;
    int t = p - 2047;
    if (t < 0) t = -t;                 // x[2047-p]
    else if (t > 4095) t = 8190 - t;   // x[10237-p]
    val = x[(b * 4096 + t) * 3 + c];
  }
  xpT[idx] = val;
}

// ---------------- build composite kernels H ----------------
__global__ __launch_bounds__(256) void k_build_H(const float* __restrict__ int_psi,
                                                 float* __restrict__ Hbuf,
                                                 int* __restrict__ meta) {
  int i   = blockIdx.x;   // scale
  int cls = blockIdx.y;   // class

  float s32; int K, d; double a;
  scale_params(i, s32, K, d, a);

  int wr = (cls < 7) ? ((cls == 0) ? 7 : cls) : ((cls == 7) ? 0 : 223);
  double ks = 4096.0 / 224.0;
  double sf = ((double)wr + 0.5) * ks - 0.5;
  int t_lo = (int)floor(sf - ks) + 1;
  int t_hi = (int)ceil(sf + ks) - 1;
  if (t_lo < 0) t_lo = 0;
  if (t_hi > 4095) t_hi = 4095;
  int nt  = t_hi - t_lo + 1;   // <= 37
  int npv = nt + 1;            // conv-point weights

  __shared__ double Wt_sh[40];
  __shared__ double v_sh[64];
  __shared__ float  kern_sh[3352];

  if (threadIdx.x == 0) {
    double Z = 0.0;
    for (int t = 0; t < nt; ++t) {
      double wv = 1.0 - fabs(sf - (double)(t + t_lo)) / ks;
      if (wv < 0.0) wv = 0.0;
      Wt_sh[t] = wv; Z += wv;
    }
    for (int t = 0; t < nt; ++t) Wt_sh[t] = Wt_sh[t] / Z;
    double sq = sqrt((double)s32);
    // v[p_lo + q] = -sqrt(s) * (Wt[q-1] - Wt[q]),  coef = -sqrt(s)*(conv[t+d+1]-conv[t+d])
    for (int q = 0; q <= nt; ++q) {
      double wm1 = (q >= 1)  ? Wt_sh[q - 1] : 0.0;
      double w0  = (q < nt)  ? Wt_sh[q]     : 0.0;
      v_sh[q] = -sq * (wm1 - w0);
    }
  }

  // flipped gathered wavelet: kernW[tau] = int_psi[clip(floor((K-1-tau)/a))]
  float* kernp = kern_sh + 40;
  int fillN = K + 80;
  for (int q = threadIdx.x; q < fillN; q += 256) {
    int tau = q - 40;
    float kv = 0.f;
    if (tau >= 0 && tau < K) {
      int u = K - 1 - tau;
      int jj = (int)floor((double)u / a);
      jj = jj < 0 ? 0 : (jj > 4095 ? 4095 : jj);
      kv = int_psi[jj];
    }
    kern_sh[q] = kv;
  }
  __syncthreads();

  int p_lo = t_lo + d;
  int Lh   = K + npv - 1;
  int kr   = (cls == 0) ? 1 : ((cls == 8) ? 31 : 0);
  int off0 = p_lo - 128 * kr;
  int shift = off0 & 3;
  int offA  = off0 - shift;
  int rowLen = (shift + Lh + 3) & ~3;

  float* row = Hbuf + (long long)(i * C_NCLS + cls) * C_HSTRIDE + C_HGUARD;
  for (int q = threadIdx.x; q < Lh; q += 256) {
    double acc = 0.0;
    for (int t = 0; t < npv; ++t) acc += v_sh[t] * (double)kernp[q - t];
    row[shift + q] = (float)acc;
  }
  if (threadIdx.x == 0) {
    meta[(i * C_NCLS + cls) * 2 + 0] = offA;
    meta[(i * C_NCLS + cls) * 2 + 1] = rowLen;
  }
}

// ---------------- main: OT[scale][w][sig] = sum_m xp[sig][m] * H_w[m] ----------------
__global__ __launch_bounds__(128) void k_cwt_main(const float* __restrict__ xpT,
                                                  const float* __restrict__ Hbuf,
                                                  const int* __restrict__ meta,
                                                  float* __restrict__ OT) {
  int chunk = blockIdx.x;     // 0..27
  int i     = blockIdx.y;     // scale
  int sig   = threadIdx.x;    // 0..127 (>=96 compute zeros)

  float acc[C_RW];
  const float* P[C_RW];
  int U0 = 0x7fffffff, U1 = 0;
#pragma unroll
  for (int j = 0; j < C_RW; ++j) {
    acc[j] = 0.f;
    int w = chunk * C_RW + j;
    int cls = (w == 0) ? 7 : ((w == 223) ? 8 : (w % 7));
    int k = w / 7;
    int base = i * C_NCLS + cls;
    int offA = meta[base * 2 + 0];
    int rl   = meta[base * 2 + 1];
    int start = offA + 128 * k;           // 4-aligned by construction
    if (start < U0) U0 = start;
    if (start + rl > U1) U1 = start + rl;
    P[j] = Hbuf + ((long long)base * C_HSTRIDE + C_HGUARD - start);
  }

  const float* xrm = xpT + (long long)U0 * C_SIGP + sig;
  for (int m = U0; m < U1; m += 4, xrm += 4 * C_SIGP) {
    float4 h[C_RW];
#pragma unroll
    for (int j = 0; j < C_RW; ++j) h[j] = *(const float4*)(P[j] + m);  // uniform -> s_load
    float xv0 = xrm[0 * C_SIGP];
    float xv1 = xrm[1 * C_SIGP];
    float xv2 = xrm[2 * C_SIGP];
    float xv3 = xrm[3 * C_SIGP];
#pragma unroll
    for (int j = 0; j < C_RW; ++j)
      acc[j] += xv0 * h[j].x + xv1 * h[j].y + xv2 * h[j].z + xv3 * h[j].w;
  }

#pragma unroll
  for (int j = 0; j < C_RW; ++j) {
    int w = chunk * C_RW + j;
    OT[((long long)i * C_NW + w) * C_SIGP + sig] = acc[j];
  }
}

// ---------------- final: scale-dim bilinear upsample 128->224 + layout ----------------
__global__ __launch_bounds__(256) void k_final(const float* __restrict__ OT,
                                               float* __restrict__ out, int total) {
  int idx = blockIdx.x * blockDim.x + threadIdx.x;
  if (idx >= total) return;
  int c = idx % 3;
  int r = idx / 3;
  int w = r % 224; r /= 224;
  int h = r % 224;
  int b = r / 224;

  float inv = 128.0f / 224.0f;               // f32 like jax
  float sg = ((float)h + 0.5f) * inv - 0.5f;
  float sgf = floorf(sg);
  int s0 = (int)sgf;
  float fr = sg - sgf;
  int sigi = c * 32 + b;

  float v;
  if (s0 < 0) {
    v = OT[(long long)(0 * 224 + w) * C_SIGP + sigi];
  } else if (s0 >= 127) {
    v = OT[((long long)127 * 224 + w) * C_SIGP + sigi];
  } else {
    float a0 = OT[((long long)s0 * 224 + w) * C_SIGP + sigi];
    float a1 = OT[((long long)(s0 + 1) * 224 + w) * C_SIGP + sigi];
    v = (1.0f - fr) * a0 + fr * a1;
  }
  out[idx] = v;
}

// ---------------- launch ----------------
extern "C" void kernel_launch(void* const* d_in, const int* in_sizes, int n_in,
                              void* d_out, int out_size, void* d_ws, size_t ws_size,
                              hipStream_t stream) {
  const float* x       = (const float*)d_in[0];   // (32,4096,3) f32
  const float* int_psi = (const float*)d_in[1];   // (4096,) f32
  float* out = (float*)d_out;

  // workspace layout (bytes): needs ~36.3 MB
  float* xpT  = (float*)d_ws;                                   // 8192*128 floats
  float* Hbuf = xpT + (long long)C_XROWS * C_SIGP;              // 1152*3776 floats
  int*   meta = (int*)(Hbuf + (long long)128 * C_NCLS * C_HSTRIDE); // 2304 ints
  float* OT   = (float*)(meta + 2304);                          // 128*224*128 floats

  hipMemsetAsync(Hbuf, 0, (size_t)128 * C_NCLS * C_HSTRIDE * sizeof(float), stream);

  k_build_xp<<<dim3((C_XROWS * C_SIGP) / 256), dim3(256), 0, stream>>>(x, xpT);
  k_build_H<<<dim3(128, C_NCLS), dim3(256), 0, stream>>>(int_psi, Hbuf, meta);
  k_cwt_main<<<dim3(28, 128), dim3(128), 0, stream>>>(xpT, Hbuf, meta, OT);
  k_final<<<dim3((out_size + 255) / 256), dim3(256), 0, stream>>>(OT, out, out_size);
}